// Round 2
// baseline (6641.104 us; speedup 1.0000x reference)
//
#include <hip/hip_runtime.h>
#include <math.h>

// Persistent Sinkhorn. One kernel runs all 21 passes.
// Per batch: 16 blocks x 256 thr (4 waves) sync via a private monotonic
// barrier (device-scope atomics + per-thread agent fences). Batches proceed
// independently, so the max(nr) tail overlaps other batches' work and
// final-pass HBM writes.
//
// Residency guarantee (instead of cooperative launch): grid = B*16 = 1024
// blocks = 256 CU x 4 blocks/CU exactly; __launch_bounds__(256,4) caps
// VGPR <= 128 so 4 blocks/CU are co-resident; LDS 6.1KB*4 = 24KB << 160KB.
// With the whole grid resident, the per-batch spin barrier cannot deadlock.
//
// Visibility (G16, per-XCD L2 non-coherent): every thread executes
// __threadfence() (agent-scope) BEFORE barrier-arrive (flush its own
// u/v/mh stores past the XCD L2) and AFTER barrier-wait (invalidate its
// caches so post-barrier loads refetch). Thread-0-only release/acquire was
// the R1 bug: it only covered thread 0's accesses.
//
// ws layout: u = B*N f32 (256KB) | v = B*M f32 (256KB) | bar = B*16 u32 (4KB)
//            | pad to 1MB | mh = B*N*M fp16 (128MB).  ws >= 1GB.

#define NEGINF (-__builtin_inff())
typedef _Float16 h16;
struct alignas(8) h4 { h16 x, y, z, w; };

#define NN 1024
#define MM 1024
#define NBLK 16  // blocks per batch

__device__ __forceinline__ float wave_max64(float v) {
#pragma unroll
    for (int o = 32; o > 0; o >>= 1) v = fmaxf(v, __shfl_xor(v, o, 64));
    return v;
}
__device__ __forceinline__ float wave_sum64(float v) {
#pragma unroll
    for (int o = 32; o > 0; o >>= 1) v += __shfl_xor(v, o, 64);
    return v;
}

__global__ void zero_bar(unsigned* bar, int n) {
    const int i = blockIdx.x * blockDim.x + threadIdx.x;
    if (i < n) bar[i] = 0;
}

// Monotonic per-batch barrier: each of NBLK blocks adds 1; wait until
// counter >= NBLK*phase. Per-thread agent fences on both sides make all
// threads' plain global stores visible across blocks/XCDs (R1 post-mortem:
// thread-0-only release/acquire is NOT sufficient).
#define BATCH_BAR()                                                            \
    do {                                                                       \
        __threadfence();                                                       \
        __syncthreads();                                                       \
        if (threadIdx.x == 0) {                                                \
            ++phase;                                                           \
            __hip_atomic_fetch_add(ctr, 1u, __ATOMIC_RELEASE,                  \
                                   __HIP_MEMORY_SCOPE_AGENT);                  \
            while (__hip_atomic_load(ctr, __ATOMIC_ACQUIRE,                    \
                                     __HIP_MEMORY_SCOPE_AGENT) <               \
                   (unsigned)(phase * NBLK))                                   \
                __builtin_amdgcn_s_sleep(8);                                   \
        }                                                                      \
        __syncthreads();                                                       \
        __threadfence();                                                       \
    } while (0)

__global__ __launch_bounds__(256, 4) void sinkhorn_fused(
    const float* __restrict__ m, const int* __restrict__ nrows,
    const int* __restrict__ ncols, float* __restrict__ u,
    float* __restrict__ v, h16* __restrict__ mh, unsigned* __restrict__ bar,
    float* __restrict__ out, int B) {
    const int b = blockIdx.x % B;    // blocks {b, b+B, ...}: same XCD under
    const int sub = blockIdx.x / B;  // round-robin dispatch (perf heuristic)
    const int w = threadIdx.x >> 6;
    const int lane = threadIdx.x & 63;
    const int wid = sub * 4 + w;  // wave id within batch [0,64)
    const int nr = nrows[b];
    const int nc = ncols[b];
    unsigned* ctr = bar + (size_t)b * 16;  // 64B-padded counter per batch
    int phase = 0;

    __shared__ float su[NN];      // 4KB: u staged for col pass
    __shared__ float pm[4][64];   // 1KB: col-pass partial max
    __shared__ float ps[4][64];   // 1KB: col-pass partial sum

    const size_t mb_off = (size_t)b * NN * MM;
    float* ub = u + (size_t)b * NN;
    float* vb = v + (size_t)b * MM;

    // ---- R0: read fp32 m, emit fp16 copy, u = -lse_j(m) ----
    for (int row = wid; row < nr; row += 64) {
        const float* rowp = m + mb_off + (size_t)row * MM;
        h16* rowh = mh + mb_off + (size_t)row * MM;
        float x[16];
#pragma unroll
        for (int k = 0; k < 4; ++k) {
            const int j = lane * 4 + k * 256;
            const float4 mv = *reinterpret_cast<const float4*>(rowp + j);
            h4 hv;
            hv.x = (h16)mv.x; hv.y = (h16)mv.y; hv.z = (h16)mv.z; hv.w = (h16)mv.w;
            *reinterpret_cast<h4*>(rowh + j) = hv;  // rows < nr always converted
            x[4 * k + 0] = (j + 0 < nc) ? mv.x : NEGINF;
            x[4 * k + 1] = (j + 1 < nc) ? mv.y : NEGINF;
            x[4 * k + 2] = (j + 2 < nc) ? mv.z : NEGINF;
            x[4 * k + 3] = (j + 3 < nc) ? mv.w : NEGINF;
        }
        if (nc > 0) {
            float mx = x[0];
#pragma unroll
            for (int e = 1; e < 16; ++e) mx = fmaxf(mx, x[e]);
            mx = wave_max64(mx);
            float s = 0.f;
#pragma unroll
            for (int e = 0; e < 16; ++e) s += __expf(x[e] - mx);
            s = wave_sum64(s);
            if (lane == 0) ub[row] = -(mx + __logf(s));
        } else if (lane == 0) {
            ub[row] = 0.f;  // no valid cols: keep u finite; outputs masked
        }
    }

    for (int t = 0; t < 10; ++t) {
        BATCH_BAR();  // u ready (and mh ready when t==0)

        // ---- col pass: v[j] = -lse_{i<nr}(mh[i,j] + u[i]) ----
        // block owns 64 cols (lane = col), 4 waves split rows 4-way.
        for (int i = threadIdx.x; i < nr; i += 256) su[i] = ub[i];
        __syncthreads();
        {
            const h16* mcol = mh + mb_off + sub * 64 + lane;
            float mx = NEGINF, s = 0.f;
            for (int i = w; i < nr; i += 4) {
                const float x = (float)mcol[(size_t)i * MM] + su[i];
                // deferred-max streaming lse: 1 exp/elem on the common path
                if (x <= mx) {
                    s += __expf(x - mx);
                } else {
                    s = s * __expf(mx - x) + 1.f;
                    mx = x;
                }
            }
            pm[w][lane] = mx;
            ps[w][lane] = s;
        }
        __syncthreads();
        if (threadIdx.x < 64) {
            float cm = pm[0][lane], cs = ps[0][lane];
#pragma unroll
            for (int r = 1; r < 4; ++r) {
                const float m2 = pm[r][lane], s2 = ps[r][lane];
                const float nm = fmaxf(cm, m2);
                cs = cs * __expf(cm - nm) + s2 * __expf(m2 - nm);
                cm = nm;
            }
            // nr==0 -> +inf here; those batches fully masked in final pass
            vb[sub * 64 + lane] = -(cm + __logf(cs));
        }

        BATCH_BAR();  // v ready
        if (t == 9) break;

        // ---- row pass: u[i] = -lse_{j<nc}(mh[i,j] + v[j]) ----
        if (nc == 0) {
            if (lane == 0)
                for (int row = wid; row < nr; row += 64) ub[row] = 0.f;
        } else {
            float4 vv[4];  // v cached in registers across all rows
#pragma unroll
            for (int k = 0; k < 4; ++k)
                vv[k] = *reinterpret_cast<const float4*>(vb + lane * 4 + k * 256);
            for (int row = wid; row < nr; row += 64) {
                const h16* rowh = mh + mb_off + (size_t)row * MM;
                float x[16];
#pragma unroll
                for (int k = 0; k < 4; ++k) {
                    const int j = lane * 4 + k * 256;
                    const h4 hv = *reinterpret_cast<const h4*>(rowh + j);
                    x[4 * k + 0] = (j + 0 < nc) ? (float)hv.x + vv[k].x : NEGINF;
                    x[4 * k + 1] = (j + 1 < nc) ? (float)hv.y + vv[k].y : NEGINF;
                    x[4 * k + 2] = (j + 2 < nc) ? (float)hv.z + vv[k].z : NEGINF;
                    x[4 * k + 3] = (j + 3 < nc) ? (float)hv.w + vv[k].w : NEGINF;
                }
                float mx = x[0];
#pragma unroll
                for (int e = 1; e < 16; ++e) mx = fmaxf(mx, x[e]);
                mx = wave_max64(mx);
                float s = 0.f;
#pragma unroll
                for (int e = 0; e < 16; ++e) s += __expf(x[e] - mx);
                s = wave_sum64(s);
                if (lane == 0) ub[row] = -(mx + __logf(s));
            }
        }
    }

    // ---- final: out = valid ? exp(m_fp32 + u + v) : 0 ----
    {
        float4 vv[4];
#pragma unroll
        for (int k = 0; k < 4; ++k)
            vv[k] = *reinterpret_cast<const float4*>(vb + lane * 4 + k * 256);
        const float4 z4 = make_float4(0.f, 0.f, 0.f, 0.f);
        for (int row = wid; row < NN; row += 64) {
            float* orow = out + mb_off + (size_t)row * MM;
            if (row < nr) {
                const float ui = ub[row];
                const float* rowp = m + mb_off + (size_t)row * MM;
#pragma unroll
                for (int k = 0; k < 4; ++k) {
                    const int j = lane * 4 + k * 256;
                    const float4 mv = *reinterpret_cast<const float4*>(rowp + j);
                    float4 r;
                    r.x = (j + 0 < nc) ? __expf(mv.x + ui + vv[k].x) : 0.f;
                    r.y = (j + 1 < nc) ? __expf(mv.y + ui + vv[k].y) : 0.f;
                    r.z = (j + 2 < nc) ? __expf(mv.z + ui + vv[k].z) : 0.f;
                    r.w = (j + 3 < nc) ? __expf(mv.w + ui + vv[k].w) : 0.f;
                    *reinterpret_cast<float4*>(orow + j) = r;
                }
            } else {
#pragma unroll
                for (int k = 0; k < 4; ++k)
                    *reinterpret_cast<float4*>(orow + lane * 4 + k * 256) = z4;
            }
        }
    }
}

extern "C" void kernel_launch(void* const* d_in, const int* in_sizes, int n_in,
                              void* d_out, int out_size, void* d_ws,
                              size_t ws_size, hipStream_t stream) {
    const float* m = (const float*)d_in[0];
    const int* nrows = (const int*)d_in[1];
    const int* ncols = (const int*)d_in[2];
    const int B = in_sizes[1];

    float* u = (float*)d_ws;                        // B*N f32
    float* v = u + (size_t)B * NN;                  // B*M f32
    unsigned* bar = (unsigned*)(v + (size_t)B * MM);// B*16 u32
    h16* mh = (h16*)((char*)d_ws + (1u << 20));     // fp16 m copy (128MB)
    float* out = (float*)d_out;

    const int nbar = B * 16;
    zero_bar<<<dim3((nbar + 255) / 256), dim3(256), 0, stream>>>(bar, nbar);

    // Plain launch under exact-capacity residency guarantee (see header).
    sinkhorn_fused<<<dim3(B * NBLK), dim3(256), 0, stream>>>(
        m, nrows, ncols, u, v, mh, bar, out, B);
}

// Round 3
// 1657.880 us; speedup vs baseline: 4.0058x; 4.0058x over previous
//
#include <hip/hip_runtime.h>
#include <math.h>

// Persistent Sinkhorn, fence-free cross-block coherence.
//
// R2 post-mortem: per-thread __threadfence() (seq-cst agent fence) emits
// buffer_wbl2 + buffer_inv (whole-L2 writeback/invalidate) PER WAVE, twice
// per barrier -> ~300us/phase of serialized L2 maintenance. 6.4ms total.
//
// R3 design: no fences, no release/acquire anywhere.
//  - u/v (8KB/batch/phase) cross block boundaries: accessed exclusively with
//    agent-scope RELAXED atomics (sc0 sc1: bypass non-coherent L1/L2, execute
//    at the L3 coherence point). Always fresh, no cache maintenance.
//  - mh (fp16 copy): written ONCE in R0 with agent-scope relaxed 64-bit
//    atomic stores (write-through; no dirty L2 line ever exists), read with
//    plain cacheable loads afterwards (no stale copy can exist: harness fill
//    poison is flushed/invalidated at dispatch boundaries, and within this
//    kernel readers first touch mh after the phase-0 barrier).
//  - Barrier: relaxed atomic add + relaxed polls. HW ordering: every wave
//    drains vmcnt(0) (sc1 store ack = at coherence point) before
//    __syncthreads; compiler ordering via "memory" clobbers.
//
// Residency: grid = B*16 = 1024 blocks = 256 CU x 4 blocks/CU exactly;
// __launch_bounds__(256,4) caps VGPR<=128; LDS 6.1KB*4 = 24KB << 160KB.
// Whole grid resident -> spin barrier cannot deadlock.
//
// ws layout: u = B*N f32 | v = B*M f32 | bar = B*16 u32 | pad to 1MB |
//            mh = B*N*M fp16 (128MB).  ws >= 1GB.

#define NEGINF (-__builtin_inff())
typedef _Float16 h16;
struct alignas(8) h4 { h16 x, y, z, w; };

#define NN 1024
#define MM 1024
#define NBLK 16  // blocks per batch

__device__ __forceinline__ float wave_max64(float v) {
#pragma unroll
    for (int o = 32; o > 0; o >>= 1) v = fmaxf(v, __shfl_xor(v, o, 64));
    return v;
}
__device__ __forceinline__ float wave_sum64(float v) {
#pragma unroll
    for (int o = 32; o > 0; o >>= 1) v += __shfl_xor(v, o, 64);
    return v;
}

// Device-coherent (sc0 sc1) accesses: relaxed agent-scope atomics.
__device__ __forceinline__ float ld_coh(const float* p) {
    return __hip_atomic_load(p, __ATOMIC_RELAXED, __HIP_MEMORY_SCOPE_AGENT);
}
__device__ __forceinline__ void st_coh(float* p, float v) {
    __hip_atomic_store(p, v, __ATOMIC_RELAXED, __HIP_MEMORY_SCOPE_AGENT);
}
__device__ __forceinline__ void st_coh64(void* p, unsigned long long v) {
    __hip_atomic_store((unsigned long long*)p, v, __ATOMIC_RELAXED,
                       __HIP_MEMORY_SCOPE_AGENT);
}

__global__ void zero_bar(unsigned* bar, int n) {
    const int i = blockIdx.x * blockDim.x + threadIdx.x;
    if (i < n) bar[i] = 0;
}

// Monotonic per-batch barrier. All atomics RELAXED (no implicit wbl2/inv).
// Each wave drains its own (sc1) stores to the coherence point first.
#define BATCH_BAR()                                                            \
    do {                                                                       \
        asm volatile("s_waitcnt vmcnt(0)" ::: "memory");                       \
        __syncthreads();                                                       \
        ++phase;                                                               \
        if (threadIdx.x == 0) {                                                \
            __hip_atomic_fetch_add(ctr, 1u, __ATOMIC_RELAXED,                  \
                                   __HIP_MEMORY_SCOPE_AGENT);                  \
            while (__hip_atomic_load(ctr, __ATOMIC_RELAXED,                    \
                                     __HIP_MEMORY_SCOPE_AGENT) <               \
                   (unsigned)(phase * NBLK))                                   \
                __builtin_amdgcn_s_sleep(8);                                   \
        }                                                                      \
        __syncthreads();                                                       \
        asm volatile("" ::: "memory");                                        \
    } while (0)

__global__ __launch_bounds__(256, 4) void sinkhorn_fused(
    const float* __restrict__ m, const int* __restrict__ nrows,
    const int* __restrict__ ncols, float* __restrict__ u,
    float* __restrict__ v, h16* __restrict__ mh, unsigned* __restrict__ bar,
    float* __restrict__ out, int B) {
    const int b = blockIdx.x % B;    // blocks {b, b+B, ...}: same XCD under
    const int sub = blockIdx.x / B;  // round-robin dispatch (perf heuristic)
    const int w = threadIdx.x >> 6;
    const int lane = threadIdx.x & 63;
    const int wid = sub * 4 + w;  // wave id within batch [0,64)
    const int nr = nrows[b];
    const int nc = ncols[b];
    unsigned* ctr = bar + (size_t)b * 16;  // 64B-padded counter per batch
    int phase = 0;

    __shared__ float su[NN];      // 4KB: u staged for col pass
    __shared__ float pm[4][64];   // 1KB: col-pass partial max
    __shared__ float ps[4][64];   // 1KB: col-pass partial sum

    const size_t mb_off = (size_t)b * NN * MM;
    float* ub = u + (size_t)b * NN;
    float* vb = v + (size_t)b * MM;

    // ---- R0: read fp32 m, emit fp16 copy (write-through), u = -lse_j(m) ----
    for (int row = wid; row < nr; row += 64) {
        const float* rowp = m + mb_off + (size_t)row * MM;
        h16* rowh = mh + mb_off + (size_t)row * MM;
        float x[16];
#pragma unroll
        for (int k = 0; k < 4; ++k) {
            const int j = lane * 4 + k * 256;
            const float4 mv = *reinterpret_cast<const float4*>(rowp + j);
            h4 hv;
            hv.x = (h16)mv.x; hv.y = (h16)mv.y; hv.z = (h16)mv.z; hv.w = (h16)mv.w;
            st_coh64(rowh + j, *reinterpret_cast<unsigned long long*>(&hv));
            x[4 * k + 0] = (j + 0 < nc) ? mv.x : NEGINF;
            x[4 * k + 1] = (j + 1 < nc) ? mv.y : NEGINF;
            x[4 * k + 2] = (j + 2 < nc) ? mv.z : NEGINF;
            x[4 * k + 3] = (j + 3 < nc) ? mv.w : NEGINF;
        }
        if (nc > 0) {
            float mx = x[0];
#pragma unroll
            for (int e = 1; e < 16; ++e) mx = fmaxf(mx, x[e]);
            mx = wave_max64(mx);
            float s = 0.f;
#pragma unroll
            for (int e = 0; e < 16; ++e) s += __expf(x[e] - mx);
            s = wave_sum64(s);
            if (lane == 0) st_coh(&ub[row], -(mx + __logf(s)));
        } else if (lane == 0) {
            st_coh(&ub[row], 0.f);  // no valid cols: keep finite; masked later
        }
    }

    for (int t = 0; t < 10; ++t) {
        BATCH_BAR();  // u ready (and mh ready when t==0)

        // ---- col pass: v[j] = -lse_{i<nr}(mh[i,j] + u[i]) ----
        // block owns 64 cols (lane = col), 4 waves split rows 4-way.
        for (int i = threadIdx.x; i < nr; i += 256) su[i] = ld_coh(&ub[i]);
        __syncthreads();
        {
            const h16* mcol = mh + mb_off + sub * 64 + lane;
            float mx = NEGINF, s = 0.f;
            for (int i = w; i < nr; i += 4) {
                const float x = (float)mcol[(size_t)i * MM] + su[i];
                // deferred-max streaming lse: 1 exp/elem on the common path
                if (x <= mx) {
                    s += __expf(x - mx);
                } else {
                    s = s * __expf(mx - x) + 1.f;
                    mx = x;
                }
            }
            pm[w][lane] = mx;
            ps[w][lane] = s;
        }
        __syncthreads();
        if (threadIdx.x < 64) {
            float cm = pm[0][lane], cs = ps[0][lane];
#pragma unroll
            for (int r = 1; r < 4; ++r) {
                const float m2 = pm[r][lane], s2 = ps[r][lane];
                const float nm = fmaxf(cm, m2);
                cs = cs * __expf(cm - nm) + s2 * __expf(m2 - nm);
                cm = nm;
            }
            // nr==0 -> +inf/NaN here; those batches fully masked in final
            st_coh(&vb[sub * 64 + lane], -(cm + __logf(cs)));
        }

        BATCH_BAR();  // v ready
        if (t == 9) break;

        // ---- row pass: u[i] = -lse_{j<nc}(mh[i,j] + v[j]) ----
        if (nc == 0) {
            if (lane == 0)
                for (int row = wid; row < nr; row += 64) st_coh(&ub[row], 0.f);
        } else {
            float4 vv[4];  // v cached in registers across all rows
#pragma unroll
            for (int k = 0; k < 4; ++k) {
                vv[k].x = ld_coh(vb + lane * 4 + k * 256 + 0);
                vv[k].y = ld_coh(vb + lane * 4 + k * 256 + 1);
                vv[k].z = ld_coh(vb + lane * 4 + k * 256 + 2);
                vv[k].w = ld_coh(vb + lane * 4 + k * 256 + 3);
            }
            for (int row = wid; row < nr; row += 64) {
                const h16* rowh = mh + mb_off + (size_t)row * MM;
                float x[16];
#pragma unroll
                for (int k = 0; k < 4; ++k) {
                    const int j = lane * 4 + k * 256;
                    const h4 hv = *reinterpret_cast<const h4*>(rowh + j);
                    x[4 * k + 0] = (j + 0 < nc) ? (float)hv.x + vv[k].x : NEGINF;
                    x[4 * k + 1] = (j + 1 < nc) ? (float)hv.y + vv[k].y : NEGINF;
                    x[4 * k + 2] = (j + 2 < nc) ? (float)hv.z + vv[k].z : NEGINF;
                    x[4 * k + 3] = (j + 3 < nc) ? (float)hv.w + vv[k].w : NEGINF;
                }
                float mx = x[0];
#pragma unroll
                for (int e = 1; e < 16; ++e) mx = fmaxf(mx, x[e]);
                mx = wave_max64(mx);
                float s = 0.f;
#pragma unroll
                for (int e = 0; e < 16; ++e) s += __expf(x[e] - mx);
                s = wave_sum64(s);
                if (lane == 0) st_coh(&ub[row], -(mx + __logf(s)));
            }
        }
    }

    // ---- final: out = valid ? exp(m_fp32 + u + v) : 0 ----
    {
        float4 vv[4];
#pragma unroll
        for (int k = 0; k < 4; ++k) {
            vv[k].x = ld_coh(vb + lane * 4 + k * 256 + 0);
            vv[k].y = ld_coh(vb + lane * 4 + k * 256 + 1);
            vv[k].z = ld_coh(vb + lane * 4 + k * 256 + 2);
            vv[k].w = ld_coh(vb + lane * 4 + k * 256 + 3);
        }
        const float4 z4 = make_float4(0.f, 0.f, 0.f, 0.f);
        for (int row = wid; row < NN; row += 64) {
            float* orow = out + mb_off + (size_t)row * MM;
            if (row < nr) {
                const float ui = ld_coh(&ub[row]);
                const float* rowp = m + mb_off + (size_t)row * MM;
#pragma unroll
                for (int k = 0; k < 4; ++k) {
                    const int j = lane * 4 + k * 256;
                    const float4 mv = *reinterpret_cast<const float4*>(rowp + j);
                    float4 r;
                    r.x = (j + 0 < nc) ? __expf(mv.x + ui + vv[k].x) : 0.f;
                    r.y = (j + 1 < nc) ? __expf(mv.y + ui + vv[k].y) : 0.f;
                    r.z = (j + 2 < nc) ? __expf(mv.z + ui + vv[k].z) : 0.f;
                    r.w = (j + 3 < nc) ? __expf(mv.w + ui + vv[k].w) : 0.f;
                    *reinterpret_cast<float4*>(orow + j) = r;
                }
            } else {
#pragma unroll
                for (int k = 0; k < 4; ++k)
                    *reinterpret_cast<float4*>(orow + lane * 4 + k * 256) = z4;
            }
        }
    }
}

extern "C" void kernel_launch(void* const* d_in, const int* in_sizes, int n_in,
                              void* d_out, int out_size, void* d_ws,
                              size_t ws_size, hipStream_t stream) {
    const float* m = (const float*)d_in[0];
    const int* nrows = (const int*)d_in[1];
    const int* ncols = (const int*)d_in[2];
    const int B = in_sizes[1];

    float* u = (float*)d_ws;                        // B*N f32
    float* v = u + (size_t)B * NN;                  // B*M f32
    unsigned* bar = (unsigned*)(v + (size_t)B * MM);// B*16 u32
    h16* mh = (h16*)((char*)d_ws + (1u << 20));     // fp16 m copy (128MB)
    float* out = (float*)d_out;

    const int nbar = B * 16;
    zero_bar<<<dim3((nbar + 255) / 256), dim3(256), 0, stream>>>(bar, nbar);

    // Plain launch under exact-capacity residency guarantee (see header).
    sinkhorn_fused<<<dim3(B * NBLK), dim3(256), 0, stream>>>(
        m, nrows, ncols, u, v, mh, bar, out, B);
}

// Round 4
// 923.382 us; speedup vs baseline: 7.1922x; 1.7954x over previous
//
#include <hip/hip_runtime.h>
#include <math.h>

// Persistent Sinkhorn, fused row+col pass (R4).
//
// R3 post-mortem: col pass = per-element 2B strided loads + serial dependent
// chain + divergent branch -> latency-bound, 10 passes; plus same-XCD batch
// mapping left CUs idle at barriers. VALUBusy 15.7%, 1368us.
//
// R4: v_new[j] = -lse_i(mh[i,j] + u_new[i]) and u_new[row] is known inside
// the row traversal. So each pass streams rows ONCE: computes u AND
// accumulates per-column online (max,sum) in registers (each lane owns the
// 16 cols it loads). Cross-wave merge in LDS -> per-block partial lse ->
// coherent scratch P -> 64-col/block finalize -> v. 10 traversals total
// (was 19), no transposed access. Mapping b=blockIdx/16: each CU hosts 4
// blocks of 4 DIFFERENT batches -> barrier waits overlap across batches.
//
// Coherence: only v and P cross block boundaries now (u is written and read
// by the same wave; mh likewise) -> v/P/u via relaxed agent-scope atomics
// (sc0 sc1, bypass non-coherent L1/L2); mh plain cached. Barrier: relaxed
// atomics + per-wave vmcnt(0) drain (R3's design, proven).
//
// Sentinels: empty col-partials use -1e30 (NOT -inf) so partial merges never
// do 0*exp(-inf - -inf)=NaN; v clamped to +-1e30 so masked-col +inf can't
// make (-inf + inf)=NaN in later row-lse.
//
// Residency: grid = B*16 = 1024 = 256 CU x 4 blocks/CU; launch_bounds(256,4)
// caps VGPR<=128; LDS 32KB*4 = 128KB <= 160KB. Whole grid resident.
//
// ws (1 GB, proven by harness 1GB poison fills): u@0 (256KB) | v@256KB |
// bar@512KB (4KB) | P@1MB (4MB) | mh@16MB (128MB).

#define NEGINF (-__builtin_inff())
#define EMPTYM (-1e30f)
typedef _Float16 h16;
struct alignas(8) h4 { h16 x, y, z, w; };

#define NN 1024
#define MM 1024
#define NBLK 16  // blocks per batch

__device__ __forceinline__ float wave_max64(float v) {
#pragma unroll
    for (int o = 32; o > 0; o >>= 1) v = fmaxf(v, __shfl_xor(v, o, 64));
    return v;
}
__device__ __forceinline__ float wave_sum64(float v) {
#pragma unroll
    for (int o = 32; o > 0; o >>= 1) v += __shfl_xor(v, o, 64);
    return v;
}

// Device-coherent (sc0 sc1) accesses: relaxed agent-scope atomics.
__device__ __forceinline__ float ld_coh(const float* p) {
    return __hip_atomic_load(p, __ATOMIC_RELAXED, __HIP_MEMORY_SCOPE_AGENT);
}
__device__ __forceinline__ void st_coh(float* p, float v) {
    __hip_atomic_store(p, v, __ATOMIC_RELAXED, __HIP_MEMORY_SCOPE_AGENT);
}

__global__ void zero_bar(unsigned* bar, int n) {
    const int i = blockIdx.x * blockDim.x + threadIdx.x;
    if (i < n) bar[i] = 0;
}

// Monotonic per-batch barrier (R3, proven). All atomics RELAXED; each wave
// drains its own (sc1) stores to the coherence point before arriving.
#define BATCH_BAR()                                                            \
    do {                                                                       \
        asm volatile("s_waitcnt vmcnt(0)" ::: "memory");                       \
        __syncthreads();                                                       \
        ++phase;                                                               \
        if (threadIdx.x == 0) {                                                \
            __hip_atomic_fetch_add(ctr, 1u, __ATOMIC_RELAXED,                  \
                                   __HIP_MEMORY_SCOPE_AGENT);                  \
            while (__hip_atomic_load(ctr, __ATOMIC_RELAXED,                    \
                                     __HIP_MEMORY_SCOPE_AGENT) <               \
                   (unsigned)(phase * NBLK))                                   \
                __builtin_amdgcn_s_sleep(8);                                   \
        }                                                                      \
        __syncthreads();                                                       \
        asm volatile("" ::: "memory");                                         \
    } while (0)

// Merge 4 waves' per-lane col partials (cm,cs)[16] -> per-block partial lse
// scalar per column -> coherent P. Col c <-> (lane=(c>>2)&63, idx=(c>>8)*4
// + (c&3)); with c = g*256 + tid: lane=(tid>>2)&63, idx=g*4+(tid&3).
__device__ __forceinline__ void merge_write(const float* cm, const float* cs,
                                            float2 (*pbuf)[16][64], int w,
                                            int lane, float* Pbs) {
    __syncthreads();
#pragma unroll
    for (int k = 0; k < 4; ++k)
#pragma unroll
        for (int e = 0; e < 4; ++e)
            pbuf[w][k * 4 + e][lane] = make_float2(cm[k * 4 + e], cs[k * 4 + e]);
    __syncthreads();
    const int t = threadIdx.x;
    const int ln = (t >> 2) & 63, eo = t & 3;
#pragma unroll
    for (int g = 0; g < 4; ++g) {
        const int idx = g * 4 + eo;
        float2 a = pbuf[0][idx][ln];
#pragma unroll
        for (int ww = 1; ww < 4; ++ww) {
            const float2 q = pbuf[ww][idx][ln];
            const float nm = fmaxf(a.x, q.x);
            a.y = a.y * __expf(a.x - nm) + q.y * __expf(q.x - nm);
            a.x = nm;
        }
        const float p = (a.y > 0.f) ? a.x + __logf(a.y) : EMPTYM;
        st_coh(Pbs + g * 256 + t, p);
    }
}

__global__ __launch_bounds__(256, 4) void sinkhorn_fused(
    const float* __restrict__ m, const int* __restrict__ nrows,
    const int* __restrict__ ncols, float* __restrict__ u,
    float* __restrict__ v, float* __restrict__ P, h16* __restrict__ mh,
    unsigned* __restrict__ bar, float* __restrict__ out, int B) {
    const int sub = blockIdx.x & (NBLK - 1);  // block within batch
    const int b = blockIdx.x >> 4;            // batch (NBLK==16)
    const int w = threadIdx.x >> 6;
    const int lane = threadIdx.x & 63;
    const int wid = sub * 4 + w;  // wave id within batch [0,64)
    const int nr = nrows[b];
    const int nc = ncols[b];
    unsigned* ctr = bar + (size_t)b * 16;  // 64B-padded counter per batch
    int phase = 0;

    __shared__ float2 pbuf[4][16][64];  // 32KB: cross-wave partial merge

    const size_t mbo = (size_t)b * NN * MM;
    float* ub = u + (size_t)b * NN;
    float* vb = v + (size_t)b * MM;
    float* Pb = P + (size_t)b * NBLK * MM;
    float* Pbs = Pb + (size_t)sub * MM;

    float cm[16], cs[16];
#pragma unroll
    for (int e = 0; e < 16; ++e) { cm[e] = EMPTYM; cs[e] = 0.f; }

    // ---- F0: fp32 m -> fp16 copy, u1 = -lse_j(m), col partials (mh+u1) ----
    if (nc > 0) {
        for (int row = wid; row < nr; row += 64) {
            const float* rowp = m + mbo + (size_t)row * MM;
            h16* rowh = mh + mbo + (size_t)row * MM;
            float xr[16], bs[16];
#pragma unroll
            for (int k = 0; k < 4; ++k) {
                const int j = lane * 4 + k * 256;
                const float4 mv = *reinterpret_cast<const float4*>(rowp + j);
                h4 hv;
                hv.x = (h16)mv.x; hv.y = (h16)mv.y;
                hv.z = (h16)mv.z; hv.w = (h16)mv.w;
                *reinterpret_cast<h4*>(rowh + j) = hv;  // same wave re-reads
                xr[4 * k + 0] = (j + 0 < nc) ? mv.x : NEGINF;
                xr[4 * k + 1] = (j + 1 < nc) ? mv.y : NEGINF;
                xr[4 * k + 2] = (j + 2 < nc) ? mv.z : NEGINF;
                xr[4 * k + 3] = (j + 3 < nc) ? mv.w : NEGINF;
                bs[4 * k + 0] = (j + 0 < nc) ? (float)hv.x : NEGINF;
                bs[4 * k + 1] = (j + 1 < nc) ? (float)hv.y : NEGINF;
                bs[4 * k + 2] = (j + 2 < nc) ? (float)hv.z : NEGINF;
                bs[4 * k + 3] = (j + 3 < nc) ? (float)hv.w : NEGINF;
            }
            float mx = xr[0];
#pragma unroll
            for (int e = 1; e < 16; ++e) mx = fmaxf(mx, xr[e]);
            mx = wave_max64(mx);
            float s = 0.f;
#pragma unroll
            for (int e = 0; e < 16; ++e) s += __expf(xr[e] - mx);
            s = wave_sum64(s);
            const float ur = -(mx + __logf(s));
            if (lane == 0) st_coh(ub + row, ur);
#pragma unroll
            for (int e = 0; e < 16; ++e) {  // col accumulate (fp16 + u1)
                const float z = bs[e] + ur;  // -inf for masked cols: safe
                const float nm = fmaxf(cm[e], z);
                cs[e] = cs[e] * __expf(cm[e] - nm) + __expf(z - nm);
                cm[e] = nm;
            }
        }
    } else {
        if (lane == 0)
            for (int row = wid; row < nr; row += 64) st_coh(ub + row, 0.f);
    }
    merge_write(cm, cs, pbuf, w, lane, Pbs);

    for (int t = 1; t <= 10; ++t) {
        BATCH_BAR();  // P partials ready

        // ---- finalize v_t: combine 16 block-partial lses per column ----
        if (threadIdx.x < 64) {
            const int col = sub * 64 + threadIdx.x;
            float mx = EMPTYM, s = 0.f;
#pragma unroll
            for (int s16 = 0; s16 < NBLK; ++s16) {
                const float p = ld_coh(Pb + s16 * MM + col);
                const float nm = fmaxf(mx, p);
                s = s * __expf(mx - nm) + __expf(p - nm);
                mx = nm;
            }
            const float vr = -(mx + __logf(s));
            st_coh(vb + col, fminf(fmaxf(vr, -1e30f), 1e30f));  // clamp inf
        }

        BATCH_BAR();  // v ready
        if (t == 10) break;

        // ---- F_t: u_{t+1} = -lse_j(mh+v_t); col partials (mh+u_{t+1}) ----
        float vv[16];
#pragma unroll
        for (int k = 0; k < 4; ++k)
#pragma unroll
            for (int e = 0; e < 4; ++e)
                vv[k * 4 + e] = ld_coh(vb + lane * 4 + k * 256 + e);
#pragma unroll
        for (int e = 0; e < 16; ++e) { cm[e] = EMPTYM; cs[e] = 0.f; }
        if (nc > 0) {
            for (int row = wid; row < nr; row += 64) {
                const h4* rp =
                    reinterpret_cast<const h4*>(mh + mbo + (size_t)row * MM);
                float bs[16];
#pragma unroll
                for (int k = 0; k < 4; ++k) {
                    const h4 hv = rp[lane + k * 64];
                    const int j = lane * 4 + k * 256;
                    bs[4 * k + 0] = (j + 0 < nc) ? (float)hv.x : NEGINF;
                    bs[4 * k + 1] = (j + 1 < nc) ? (float)hv.y : NEGINF;
                    bs[4 * k + 2] = (j + 2 < nc) ? (float)hv.z : NEGINF;
                    bs[4 * k + 3] = (j + 3 < nc) ? (float)hv.w : NEGINF;
                }
                float mx = NEGINF;
#pragma unroll
                for (int e = 0; e < 16; ++e) mx = fmaxf(mx, bs[e] + vv[e]);
                mx = wave_max64(mx);
                float s = 0.f;
#pragma unroll
                for (int e = 0; e < 16; ++e) s += __expf(bs[e] + vv[e] - mx);
                s = wave_sum64(s);
                const float ur = -(mx + __logf(s));
                if (lane == 0) st_coh(ub + row, ur);
#pragma unroll
                for (int e = 0; e < 16; ++e) {
                    const float z = bs[e] + ur;
                    const float nm = fmaxf(cm[e], z);
                    cs[e] = cs[e] * __expf(cm[e] - nm) + __expf(z - nm);
                    cm[e] = nm;
                }
            }
        }
        merge_write(cm, cs, pbuf, w, lane, Pbs);
    }

    // ---- final: out = valid ? exp(m_fp32 + u10 + v10) : 0 ----
    {
        float vv[16];
#pragma unroll
        for (int k = 0; k < 4; ++k)
#pragma unroll
            for (int e = 0; e < 4; ++e)
                vv[k * 4 + e] = ld_coh(vb + lane * 4 + k * 256 + e);
        const float4 z4 = make_float4(0.f, 0.f, 0.f, 0.f);
        for (int row = wid; row < NN; row += 64) {
            float* orow = out + mbo + (size_t)row * MM;
            if (row < nr) {
                const float ui = ld_coh(ub + row);
                const float* rowp = m + mbo + (size_t)row * MM;
#pragma unroll
                for (int k = 0; k < 4; ++k) {
                    const int j = lane * 4 + k * 256;
                    const float4 mv = *reinterpret_cast<const float4*>(rowp + j);
                    float4 r;
                    r.x = (j + 0 < nc) ? __expf(mv.x + ui + vv[4 * k + 0]) : 0.f;
                    r.y = (j + 1 < nc) ? __expf(mv.y + ui + vv[4 * k + 1]) : 0.f;
                    r.z = (j + 2 < nc) ? __expf(mv.z + ui + vv[4 * k + 2]) : 0.f;
                    r.w = (j + 3 < nc) ? __expf(mv.w + ui + vv[4 * k + 3]) : 0.f;
                    *reinterpret_cast<float4*>(orow + j) = r;
                }
            } else {
#pragma unroll
                for (int k = 0; k < 4; ++k)
                    *reinterpret_cast<float4*>(orow + lane * 4 + k * 256) = z4;
            }
        }
    }
}

extern "C" void kernel_launch(void* const* d_in, const int* in_sizes, int n_in,
                              void* d_out, int out_size, void* d_ws,
                              size_t ws_size, hipStream_t stream) {
    const float* m = (const float*)d_in[0];
    const int* nrows = (const int*)d_in[1];
    const int* ncols = (const int*)d_in[2];
    const int B = in_sizes[1];

    char* ws = (char*)d_ws;
    float* u = (float*)ws;                          // 256KB
    float* v = (float*)(ws + (256u << 10));         // 256KB
    unsigned* bar = (unsigned*)(ws + (512u << 10)); // 4KB
    float* P = (float*)(ws + (1u << 20));           // 4MB
    h16* mh = (h16*)(ws + (16u << 20));             // 128MB
    float* out = (float*)d_out;

    const int nbar = B * 16;
    zero_bar<<<dim3((nbar + 255) / 256), dim3(256), 0, stream>>>(bar, nbar);

    // Plain launch under exact-capacity residency guarantee (see header).
    sinkhorn_fused<<<dim3(B * NBLK), dim3(256), 0, stream>>>(
        m, nrows, ncols, u, v, P, mh, bar, out, B);
}

// Round 5
// 758.994 us; speedup vs baseline: 8.7499x; 1.2166x over previous
//
#include <hip/hip_runtime.h>
#include <math.h>

// Persistent Sinkhorn R5: 1 barrier/iteration, 1 exp/element.
//
// R4 post-mortem: 2 barriers x 10 iters dominated stall (~15-20us skew each);
// online col-lse burned 2 extra exps/element; float2 LDS merge bank-conflicted.
//
// R5 key identities:
//   u_new[i] = -(mx_i + log s_i)  (row lse over z = mh+v)
//   exp(mh+v+u_new) = exp(z - mx)/s = p_e * rcp(s)   <- reuse row-pass exps!
//   v_new[j] = v_old[j] - log( sum_i exp(mh+v_old+u_new) )
// So col partials are PLAIN SUMS (cs[e] += p_e*rs): no extra transcendentals.
// Plain sums make v-finalize cheap -> every block finalizes the FULL v
// redundantly (reads all 16 blocks' partials, 64KB coherent) into local LDS
// -> no v-broadcast barrier. 10 barriers total (was 20).
//
// P double-buffered: iter t reads parity t&1, row pass writes parity (t+1)&1.
// A block can't get 2 iters ahead through one barrier -> no WAR race.
//
// Masked cols: vvm[e] = -1e30 folded into z -> exp underflows to exact 0;
// their CS=0 -> v=+inf -> clamped to 1e30, but clamped value is never
// consumed (always re-masked). nc==0 / nr==0 degenerate cases give zeros.
//
// Coherence: only P crosses blocks -> relaxed agent-scope atomics (sc0 sc1,
// L3 coherence point). u/v live in LDS (block-local). mh written/read by the
// same wave only. Barrier: relaxed atomics + per-wave vmcnt(0) drain (proven
// R3/R4).
//
// Residency: grid = B*16 = 1024 = 256 CU x 4 blocks/CU; launch_bounds(256,4);
// LDS 28KB x 4 = 112KB <= 160KB. Whole grid resident -> spin barrier safe.
//
// ws: bar@0 (4KB) | P@1MB (2 x 4MB) | mh@16MB (128MB). ws >= 1GB.

#define NEGINF (-__builtin_inff())
#define BIGNEG (-1e30f)
typedef _Float16 h16;
struct alignas(16) h8 { h16 h[8]; };

#define NN 1024
#define MM 1024
#define NBLK 16  // blocks per batch

__device__ __forceinline__ float wave_max64(float v) {
#pragma unroll
    for (int o = 32; o > 0; o >>= 1) v = fmaxf(v, __shfl_xor(v, o, 64));
    return v;
}
__device__ __forceinline__ float wave_sum64(float v) {
#pragma unroll
    for (int o = 32; o > 0; o >>= 1) v += __shfl_xor(v, o, 64);
    return v;
}

__device__ __forceinline__ float ld_coh(const float* p) {
    return __hip_atomic_load(p, __ATOMIC_RELAXED, __HIP_MEMORY_SCOPE_AGENT);
}
__device__ __forceinline__ void st_coh(float* p, float v) {
    __hip_atomic_store(p, v, __ATOMIC_RELAXED, __HIP_MEMORY_SCOPE_AGENT);
}

__global__ void zero_bar(unsigned* bar, int n) {
    const int i = blockIdx.x * blockDim.x + threadIdx.x;
    if (i < n) bar[i] = 0;
}

// Monotonic per-batch barrier (proven R3/R4). Relaxed atomics; each wave
// drains its own sc1 stores to the coherence point before arriving.
#define BATCH_BAR()                                                            \
    do {                                                                       \
        asm volatile("s_waitcnt vmcnt(0)" ::: "memory");                       \
        __syncthreads();                                                       \
        ++phase;                                                               \
        if (threadIdx.x == 0) {                                                \
            __hip_atomic_fetch_add(ctr, 1u, __ATOMIC_RELAXED,                  \
                                   __HIP_MEMORY_SCOPE_AGENT);                  \
            while (__hip_atomic_load(ctr, __ATOMIC_RELAXED,                    \
                                     __HIP_MEMORY_SCOPE_AGENT) <               \
                   (unsigned)(phase * NBLK))                                   \
                __builtin_amdgcn_s_sleep(8);                                   \
        }                                                                      \
        __syncthreads();                                                       \
        asm volatile("" ::: "memory");                                         \
    } while (0)

__global__ __launch_bounds__(256, 4) void sinkhorn_fused(
    const float* __restrict__ m, const int* __restrict__ nrows,
    const int* __restrict__ ncols, float* __restrict__ P,
    h16* __restrict__ mh, unsigned* __restrict__ bar, float* __restrict__ out,
    int B) {
    const int sub = blockIdx.x & (NBLK - 1);  // block within batch
    const int b = blockIdx.x >> 4;            // batch
    const int w = threadIdx.x >> 6;
    const int lane = threadIdx.x & 63;
    const int wid = sub * 4 + w;  // wave id within batch [0,64)
    const int tid = threadIdx.x;
    const int nr = nrows[b];
    const int nc = ncols[b];
    unsigned* ctr = bar + (size_t)b * 16;
    int phase = 0;

    __shared__ float pbuf[4][16][64];  // 16KB cross-wave partial merge
    __shared__ float csum[MM];         // 4KB merged block partial
    __shared__ float vloc[MM];         // 4KB full v, block-local
    __shared__ float uloc[NN];         // 4KB u for this block's rows

    const size_t mbo = (size_t)b * NN * MM;
    const size_t Psz = (size_t)B * NBLK * MM;         // one parity buffer
    float* Pw0 = P + (size_t)b * NBLK * MM + (size_t)sub * MM;  // write base
    const float* Pr0 = P + (size_t)b * NBLK * MM;               // read base

    float cs[16];
#pragma unroll
    for (int e = 0; e < 16; ++e) cs[e] = 0.f;

    // ---- F0: fp32 m -> fp16 mh, u1 = -lse_j(m), col partials sum p/s ----
    {
        float mk[16];
#pragma unroll
        for (int k = 0; k < 2; ++k)
#pragma unroll
            for (int e = 0; e < 8; ++e) {
                const int col = lane * 8 + k * 512 + e;
                mk[k * 8 + e] = (col < nc) ? 0.f : BIGNEG;
            }
        if (nc > 0) {
            for (int row = wid; row < nr; row += 64) {
                const float* rowp = m + mbo + (size_t)row * MM;
                h16* rowh = mh + mbo + (size_t)row * MM;
                float xr[16], p[16];
#pragma unroll
                for (int k = 0; k < 2; ++k) {
                    const int j = lane * 8 + k * 512;
                    const float4 a = *reinterpret_cast<const float4*>(rowp + j);
                    const float4 c = *reinterpret_cast<const float4*>(rowp + j + 4);
                    h8 hv;
                    hv.h[0] = (h16)a.x; hv.h[1] = (h16)a.y;
                    hv.h[2] = (h16)a.z; hv.h[3] = (h16)a.w;
                    hv.h[4] = (h16)c.x; hv.h[5] = (h16)c.y;
                    hv.h[6] = (h16)c.z; hv.h[7] = (h16)c.w;
                    *reinterpret_cast<h8*>(rowh + j) = hv;
                    xr[k * 8 + 0] = a.x + mk[k * 8 + 0];
                    xr[k * 8 + 1] = a.y + mk[k * 8 + 1];
                    xr[k * 8 + 2] = a.z + mk[k * 8 + 2];
                    xr[k * 8 + 3] = a.w + mk[k * 8 + 3];
                    xr[k * 8 + 4] = c.x + mk[k * 8 + 4];
                    xr[k * 8 + 5] = c.y + mk[k * 8 + 5];
                    xr[k * 8 + 6] = c.z + mk[k * 8 + 6];
                    xr[k * 8 + 7] = c.w + mk[k * 8 + 7];
                }
                float mx = xr[0];
#pragma unroll
                for (int e = 1; e < 16; ++e) mx = fmaxf(mx, xr[e]);
                mx = wave_max64(mx);
                float s = 0.f;
#pragma unroll
                for (int e = 0; e < 16; ++e) { p[e] = __expf(xr[e] - mx); s += p[e]; }
                s = wave_sum64(s);
                const float rs = __builtin_amdgcn_rcpf(s);
#pragma unroll
                for (int e = 0; e < 16; ++e) cs[e] += p[e] * rs;
                if (lane == 0) uloc[row] = -(mx + __logf(s));
            }
        } else {
            if (lane == 0)
                for (int row = wid; row < nr; row += 64) uloc[row] = 0.f;
        }
    }

    for (int t = 1; t <= 10; ++t) {
        // ---- merge 4 waves -> block partial -> coherent P[parity t&1] ----
        __syncthreads();  // pbuf/csum reuse safe; prev vloc readers done
#pragma unroll
        for (int e = 0; e < 16; ++e) pbuf[w][e][lane] = cs[e];
        __syncthreads();
#pragma unroll
        for (int q = 0; q < 4; ++q) {
            const int idx = q * 4 + (tid >> 6);  // 0..15
            const int ln = tid & 63;
            float vsum = pbuf[0][idx][ln];
#pragma unroll
            for (int ww = 1; ww < 4; ++ww) vsum += pbuf[ww][idx][ln];
            csum[ln * 8 + (idx >> 3) * 512 + (idx & 7)] = vsum;
        }
        __syncthreads();
        {
            float* Pw = Pw0 + (t & 1) * Psz;
#pragma unroll
            for (int e = 0; e < 4; ++e) st_coh(Pw + tid * 4 + e, csum[tid * 4 + e]);
        }

        BATCH_BAR();  // all 16 blocks' partials at coherence point

        // ---- redundant local finalize: full v for all 1024 cols ----
        {
            const float* Pr = Pr0 + (t & 1) * Psz;
            float CS[4];
#pragma unroll
            for (int e = 0; e < 4; ++e) CS[e] = 0.f;
#pragma unroll
            for (int s16 = 0; s16 < NBLK; ++s16)
#pragma unroll
                for (int e = 0; e < 4; ++e)
                    CS[e] += ld_coh(Pr + s16 * MM + tid * 4 + e);
#pragma unroll
            for (int e = 0; e < 4; ++e) {
                const float vp = (t == 1) ? 0.f : vloc[tid * 4 + e];
                const float vn = vp - __logf(CS[e]);  // CS=0 -> +inf -> clamp
                vloc[tid * 4 + e] = fminf(fmaxf(vn, BIGNEG), 1e30f);
            }
        }
        __syncthreads();  // vloc ready for all waves
        if (t == 10) break;

        // ---- row pass: u_{t+1} = -lse_j(mh+v_t); col sums for v_{t+1} ----
        float vvm[16];
#pragma unroll
        for (int k = 0; k < 2; ++k)
#pragma unroll
            for (int e = 0; e < 8; ++e) {
                const int col = lane * 8 + k * 512 + e;
                vvm[k * 8 + e] = (col < nc) ? vloc[col] : BIGNEG;
            }
#pragma unroll
        for (int e = 0; e < 16; ++e) cs[e] = 0.f;
        if (nc > 0) {
            for (int row = wid; row < nr; row += 64) {
                const h16* rowh = mh + mbo + (size_t)row * MM;
                float z[16], p[16];
#pragma unroll
                for (int k = 0; k < 2; ++k) {
                    const h8 hv =
                        *reinterpret_cast<const h8*>(rowh + lane * 8 + k * 512);
#pragma unroll
                    for (int e = 0; e < 8; ++e)
                        z[k * 8 + e] = (float)hv.h[e] + vvm[k * 8 + e];
                }
                float mx = z[0];
#pragma unroll
                for (int e = 1; e < 16; ++e) mx = fmaxf(mx, z[e]);
                mx = wave_max64(mx);
                float s = 0.f;
#pragma unroll
                for (int e = 0; e < 16; ++e) { p[e] = __expf(z[e] - mx); s += p[e]; }
                s = wave_sum64(s);
                const float rs = __builtin_amdgcn_rcpf(s);
#pragma unroll
                for (int e = 0; e < 16; ++e) cs[e] += p[e] * rs;
                if (lane == 0) uloc[row] = -(mx + __logf(s));
            }
        } else {
            if (lane == 0)
                for (int row = wid; row < nr; row += 64) uloc[row] = 0.f;
        }
    }

    // ---- final: out = exp(m + u10 + v10); masked via vvm/-rows -> 0 ----
    {
        float vvm[16];
#pragma unroll
        for (int k = 0; k < 2; ++k)
#pragma unroll
            for (int e = 0; e < 8; ++e) {
                const int col = lane * 8 + k * 512 + e;
                vvm[k * 8 + e] = (col < nc) ? vloc[col] : BIGNEG;
            }
        const float4 z4 = make_float4(0.f, 0.f, 0.f, 0.f);
        for (int row = wid; row < NN; row += 64) {
            float* orow = out + mbo + (size_t)row * MM;
            if (row < nr) {
                const float ui = uloc[row];
                const float* rowp = m + mbo + (size_t)row * MM;
#pragma unroll
                for (int k = 0; k < 2; ++k) {
                    const int j = lane * 8 + k * 512;
                    const float4 a = *reinterpret_cast<const float4*>(rowp + j);
                    const float4 c = *reinterpret_cast<const float4*>(rowp + j + 4);
                    float4 r0, r1;
                    r0.x = __expf(a.x + ui + vvm[k * 8 + 0]);
                    r0.y = __expf(a.y + ui + vvm[k * 8 + 1]);
                    r0.z = __expf(a.z + ui + vvm[k * 8 + 2]);
                    r0.w = __expf(a.w + ui + vvm[k * 8 + 3]);
                    r1.x = __expf(c.x + ui + vvm[k * 8 + 4]);
                    r1.y = __expf(c.y + ui + vvm[k * 8 + 5]);
                    r1.z = __expf(c.z + ui + vvm[k * 8 + 6]);
                    r1.w = __expf(c.w + ui + vvm[k * 8 + 7]);
                    *reinterpret_cast<float4*>(orow + j) = r0;
                    *reinterpret_cast<float4*>(orow + j + 4) = r1;
                }
            } else {
#pragma unroll
                for (int k = 0; k < 2; ++k) {
                    const int j = lane * 8 + k * 512;
                    *reinterpret_cast<float4*>(orow + j) = z4;
                    *reinterpret_cast<float4*>(orow + j + 4) = z4;
                }
            }
        }
    }
}

extern "C" void kernel_launch(void* const* d_in, const int* in_sizes, int n_in,
                              void* d_out, int out_size, void* d_ws,
                              size_t ws_size, hipStream_t stream) {
    const float* m = (const float*)d_in[0];
    const int* nrows = (const int*)d_in[1];
    const int* ncols = (const int*)d_in[2];
    const int B = in_sizes[1];

    char* ws = (char*)d_ws;
    unsigned* bar = (unsigned*)ws;             // 4KB
    float* P = (float*)(ws + (1u << 20));      // 2 x B*16*1024*4 = 8MB
    h16* mh = (h16*)(ws + (16u << 20));        // 128MB
    float* out = (float*)d_out;

    const int nbar = B * 16;
    zero_bar<<<dim3((nbar + 255) / 256), dim3(256), 0, stream>>>(bar, nbar);

    sinkhorn_fused<<<dim3(B * NBLK), dim3(256), 0, stream>>>(
        m, nrows, ncols, P, mh, bar, out, B);
}

// Round 6
// 600.226 us; speedup vs baseline: 11.0643x; 1.2645x over previous
//
#include <hip/hip_runtime.h>
#include <math.h>

// Persistent Sinkhorn R6.
// R5 post-mortem: stall-bound (VALU 22%, HBM 28%). Three fixes:
//  1. Final pass reads mh (fp16, L3-warm) instead of m (fp32, HBM cold):
//     -256MB HBM. Error +<=0.002 absmax (fp16 on |m|<=5), budget 0.0185. 
//  2. Conflict-free LDS merge (pbuf[4][64][17] transposed+padded) and fully
//     coalesced P layout (col = tid + q*256 for merge store AND finalize
//     load): kills the 9.3M bank-conflict cycles + 4B strided coherent ops.
//  3. ILP: steady row pass processes 2 rows/iter (independent reduce chains,
//     4 loads issued up front); F0 prefetches next row while reducing.
// Everything else (proven R3-R5): per-batch monotonic barrier w/ relaxed
// agent atomics + vmcnt drain; sc0sc1 coherent P; 1 barrier/iter; plain-sum
// col partials via exp reuse (v_new = v_old - log sum p/s).
//
// ws: bar@0 (4KB) | P@1MB (2 x 4MB) | mh@16MB (128MB). ws >= 1GB.

#define BIGNEG (-1e30f)
typedef _Float16 h16;
struct alignas(16) h8 { h16 h[8]; };

#define NN 1024
#define MM 1024
#define NBLK 16  // blocks per batch

__device__ __forceinline__ float wave_max64(float v) {
#pragma unroll
    for (int o = 32; o > 0; o >>= 1) v = fmaxf(v, __shfl_xor(v, o, 64));
    return v;
}
__device__ __forceinline__ float wave_sum64(float v) {
#pragma unroll
    for (int o = 32; o > 0; o >>= 1) v += __shfl_xor(v, o, 64);
    return v;
}

__device__ __forceinline__ float ld_coh(const float* p) {
    return __hip_atomic_load(p, __ATOMIC_RELAXED, __HIP_MEMORY_SCOPE_AGENT);
}
__device__ __forceinline__ void st_coh(float* p, float v) {
    __hip_atomic_store(p, v, __ATOMIC_RELAXED, __HIP_MEMORY_SCOPE_AGENT);
}

__global__ void zero_bar(unsigned* bar, int n) {
    const int i = blockIdx.x * blockDim.x + threadIdx.x;
    if (i < n) bar[i] = 0;
}

// Monotonic per-batch barrier (proven R3-R5). Relaxed atomics; each wave
// drains its own sc1 stores to the coherence point before arriving.
#define BATCH_BAR()                                                            \
    do {                                                                       \
        asm volatile("s_waitcnt vmcnt(0)" ::: "memory");                       \
        __syncthreads();                                                       \
        ++phase;                                                               \
        if (threadIdx.x == 0) {                                                \
            __hip_atomic_fetch_add(ctr, 1u, __ATOMIC_RELAXED,                  \
                                   __HIP_MEMORY_SCOPE_AGENT);                  \
            while (__hip_atomic_load(ctr, __ATOMIC_RELAXED,                    \
                                     __HIP_MEMORY_SCOPE_AGENT) <               \
                   (unsigned)(phase * NBLK))                                   \
                __builtin_amdgcn_s_sleep(8);                                   \
        }                                                                      \
        __syncthreads();                                                       \
        asm volatile("" ::: "memory");                                         \
    } while (0)

// lse-reduce 16 per-lane values (z overwritten with exp(z-mx)); accumulate
// col partial sums cs[e] += exp(z-mx)/s; return u = -(mx + log s).
__device__ __forceinline__ void reduce16(float* z, float* cs, float& uout) {
    float mx = z[0];
#pragma unroll
    for (int e = 1; e < 16; ++e) mx = fmaxf(mx, z[e]);
    mx = wave_max64(mx);
    float s = 0.f;
#pragma unroll
    for (int e = 0; e < 16; ++e) { z[e] = __expf(z[e] - mx); s += z[e]; }
    s = wave_sum64(s);
    const float rs = __builtin_amdgcn_rcpf(s);
#pragma unroll
    for (int e = 0; e < 16; ++e) cs[e] += z[e] * rs;
    uout = -(mx + __logf(s));
}

__global__ __launch_bounds__(256, 4) void sinkhorn_fused(
    const float* __restrict__ m, const int* __restrict__ nrows,
    const int* __restrict__ ncols, float* __restrict__ P,
    h16* __restrict__ mh, unsigned* __restrict__ bar, float* __restrict__ out,
    int B) {
    const int sub = blockIdx.x & (NBLK - 1);
    const int b = blockIdx.x >> 4;
    const int w = threadIdx.x >> 6;
    const int lane = threadIdx.x & 63;
    const int wid = sub * 4 + w;  // wave id within batch [0,64)
    const int tid = threadIdx.x;
    const int nr = nrows[b];
    const int nc = ncols[b];
    unsigned* ctr = bar + (size_t)b * 16;
    int phase = 0;

    __shared__ float pbuf[4][64][17];  // 17KB padded: conflict-free merge
    __shared__ float vloc[MM];         // 4KB full v, block-local
    __shared__ float uloc[NN];         // 4KB u for this block's rows

    const size_t mbo = (size_t)b * NN * MM;
    const size_t Psz = (size_t)B * NBLK * MM;  // one parity buffer (4MB)
    float* Pw0 = P + (size_t)b * NBLK * MM + (size_t)sub * MM;
    const float* Pr0 = P + (size_t)b * NBLK * MM;

    float cs[16];
#pragma unroll
    for (int e = 0; e < 16; ++e) cs[e] = 0.f;

    // ---- F0: fp32 m -> fp16 mh, u1 = -lse_j(m), col partial sums ----
    if (nc > 0) {
        float mk[16];
#pragma unroll
        for (int e = 0; e < 16; ++e) {
            const int col = lane * 8 + (e >> 3) * 512 + (e & 7);
            mk[e] = (col < nc) ? 0.f : BIGNEG;
        }
        int row = wid;
        float4 A0, A1, A2, A3;
        if (row < nr) {
            const float* rp = m + mbo + (size_t)row * MM + lane * 8;
            A0 = *reinterpret_cast<const float4*>(rp);
            A1 = *reinterpret_cast<const float4*>(rp + 4);
            A2 = *reinterpret_cast<const float4*>(rp + 512);
            A3 = *reinterpret_cast<const float4*>(rp + 516);
        }
        while (row < nr) {
            const int nx = row + 64;
            float4 N0, N1, N2, N3;
            if (nx < nr) {  // prefetch next row while reducing current
                const float* rq = m + mbo + (size_t)nx * MM + lane * 8;
                N0 = *reinterpret_cast<const float4*>(rq);
                N1 = *reinterpret_cast<const float4*>(rq + 4);
                N2 = *reinterpret_cast<const float4*>(rq + 512);
                N3 = *reinterpret_cast<const float4*>(rq + 516);
            }
            float z[16];
            *reinterpret_cast<float4*>(&z[0]) = A0;
            *reinterpret_cast<float4*>(&z[4]) = A1;
            *reinterpret_cast<float4*>(&z[8]) = A2;
            *reinterpret_cast<float4*>(&z[12]) = A3;
            h8 hv0, hv1;
#pragma unroll
            for (int e = 0; e < 8; ++e) hv0.h[e] = (h16)z[e];
#pragma unroll
            for (int e = 0; e < 8; ++e) hv1.h[e] = (h16)z[8 + e];
            h16* rh = mh + mbo + (size_t)row * MM + lane * 8;
            *reinterpret_cast<h8*>(rh) = hv0;
            *reinterpret_cast<h8*>(rh + 512) = hv1;
#pragma unroll
            for (int e = 0; e < 16; ++e) z[e] += mk[e];
            float u;
            reduce16(z, cs, u);
            if (lane == 0) uloc[row] = u;
            A0 = N0; A1 = N1; A2 = N2; A3 = N3;
            row = nx;
        }
    } else {
        if (lane == 0)
            for (int row = wid; row < nr; row += 64) uloc[row] = 0.f;
    }

    for (int t = 1; t <= 10; ++t) {
        // ---- merge 4 waves' cs -> block partial -> coherent P[t&1] ----
        // (own pbuf slice; prior readers all passed BATCH_BAR(t-1))
#pragma unroll
        for (int e = 0; e < 16; ++e) pbuf[w][lane][e] = cs[e];
        __syncthreads();
        {
            float* Pw = Pw0 + (size_t)(t & 1) * Psz;
#pragma unroll
            for (int q = 0; q < 4; ++q) {
                const int col = tid + q * 256;  // coalesced
                const int ls = (col >> 3) & 63;
                const int ei = ((col >> 9) << 3) | (col & 7);
                const float sum = pbuf[0][ls][ei] + pbuf[1][ls][ei] +
                                  pbuf[2][ls][ei] + pbuf[3][ls][ei];
                st_coh(Pw + col, sum);
            }
        }

        BATCH_BAR();  // all 16 blocks' partials at coherence point

        // ---- redundant local finalize: full v for all 1024 cols ----
        {
            const float* Pr = Pr0 + (size_t)(t & 1) * Psz;
#pragma unroll
            for (int q = 0; q < 4; ++q) {
                const int col = tid + q * 256;  // coalesced
                float CS = 0.f;
#pragma unroll
                for (int s16 = 0; s16 < NBLK; ++s16)
                    CS += ld_coh(Pr + s16 * MM + col);
                const float vp = (t == 1) ? 0.f : vloc[col];
                const float vn = vp - __logf(CS);  // CS=0 -> +inf -> clamp
                vloc[col] = fminf(fmaxf(vn, BIGNEG), 1e30f);
            }
        }
        __syncthreads();  // vloc ready for all waves
        if (t == 10) break;

        // ---- row pass: u_{t+1} = -lse_j(mh+v_t); col sums for v_{t+1} ----
        float vvm[16];
        {
            float tmp[16];
            *reinterpret_cast<float4*>(&tmp[0]) =
                *reinterpret_cast<const float4*>(&vloc[lane * 8]);
            *reinterpret_cast<float4*>(&tmp[4]) =
                *reinterpret_cast<const float4*>(&vloc[lane * 8 + 4]);
            *reinterpret_cast<float4*>(&tmp[8]) =
                *reinterpret_cast<const float4*>(&vloc[lane * 8 + 512]);
            *reinterpret_cast<float4*>(&tmp[12]) =
                *reinterpret_cast<const float4*>(&vloc[lane * 8 + 516]);
#pragma unroll
            for (int e = 0; e < 16; ++e) {
                const int col = lane * 8 + (e >> 3) * 512 + (e & 7);
                vvm[e] = (col < nc) ? tmp[e] : BIGNEG;
            }
        }
#pragma unroll
        for (int e = 0; e < 16; ++e) cs[e] = 0.f;
        if (nc > 0) {
            int row = wid;
            // dual-row: two independent reduce chains, loads issued first
            while (row + 64 < nr) {
                const h16* r0 = mh + mbo + (size_t)row * MM + lane * 8;
                const h16* r1 = r0 + (size_t)64 * MM;
                const h8 a0 = *reinterpret_cast<const h8*>(r0);
                const h8 a1 = *reinterpret_cast<const h8*>(r0 + 512);
                const h8 b0 = *reinterpret_cast<const h8*>(r1);
                const h8 b1 = *reinterpret_cast<const h8*>(r1 + 512);
                float z0[16], z1[16];
#pragma unroll
                for (int e = 0; e < 8; ++e) {
                    z0[e] = (float)a0.h[e] + vvm[e];
                    z0[8 + e] = (float)a1.h[e] + vvm[8 + e];
                    z1[e] = (float)b0.h[e] + vvm[e];
                    z1[8 + e] = (float)b1.h[e] + vvm[8 + e];
                }
                float u0, u1;
                reduce16(z0, cs, u0);
                reduce16(z1, cs, u1);
                if (lane == 0) { uloc[row] = u0; uloc[row + 64] = u1; }
                row += 128;
            }
            if (row < nr) {
                const h16* r0 = mh + mbo + (size_t)row * MM + lane * 8;
                const h8 a0 = *reinterpret_cast<const h8*>(r0);
                const h8 a1 = *reinterpret_cast<const h8*>(r0 + 512);
                float z0[16];
#pragma unroll
                for (int e = 0; e < 8; ++e) {
                    z0[e] = (float)a0.h[e] + vvm[e];
                    z0[8 + e] = (float)a1.h[e] + vvm[8 + e];
                }
                float u0;
                reduce16(z0, cs, u0);
                if (lane == 0) uloc[row] = u0;
            }
        }
    }

    // ---- final: out = exp(mh + u10 + v10) (fp16 m, L3-warm; -256MB HBM) ----
    {
        float vvm[16];
        float tmp[16];
        *reinterpret_cast<float4*>(&tmp[0]) =
            *reinterpret_cast<const float4*>(&vloc[lane * 8]);
        *reinterpret_cast<float4*>(&tmp[4]) =
            *reinterpret_cast<const float4*>(&vloc[lane * 8 + 4]);
        *reinterpret_cast<float4*>(&tmp[8]) =
            *reinterpret_cast<const float4*>(&vloc[lane * 8 + 512]);
        *reinterpret_cast<float4*>(&tmp[12]) =
            *reinterpret_cast<const float4*>(&vloc[lane * 8 + 516]);
#pragma unroll
        for (int e = 0; e < 16; ++e) {
            const int col = lane * 8 + (e >> 3) * 512 + (e & 7);
            vvm[e] = (col < nc) ? tmp[e] : BIGNEG;
        }
        const float4 z4 = make_float4(0.f, 0.f, 0.f, 0.f);
        for (int row = wid; row < NN; row += 64) {
            float* orow = out + mbo + (size_t)row * MM + lane * 8;
            if (row < nr) {
                const float ui = uloc[row];
                const h16* rh = mh + mbo + (size_t)row * MM + lane * 8;
                const h8 h0 = *reinterpret_cast<const h8*>(rh);
                const h8 h1 = *reinterpret_cast<const h8*>(rh + 512);
                float r[16];
#pragma unroll
                for (int e = 0; e < 8; ++e) {
                    r[e] = __expf((float)h0.h[e] + ui + vvm[e]);
                    r[8 + e] = __expf((float)h1.h[e] + ui + vvm[8 + e]);
                }
                *reinterpret_cast<float4*>(orow) =
                    *reinterpret_cast<float4*>(&r[0]);
                *reinterpret_cast<float4*>(orow + 4) =
                    *reinterpret_cast<float4*>(&r[4]);
                *reinterpret_cast<float4*>(orow + 512) =
                    *reinterpret_cast<float4*>(&r[8]);
                *reinterpret_cast<float4*>(orow + 516) =
                    *reinterpret_cast<float4*>(&r[12]);
            } else {
                *reinterpret_cast<float4*>(orow) = z4;
                *reinterpret_cast<float4*>(orow + 4) = z4;
                *reinterpret_cast<float4*>(orow + 512) = z4;
                *reinterpret_cast<float4*>(orow + 516) = z4;
            }
        }
    }
}

extern "C" void kernel_launch(void* const* d_in, const int* in_sizes, int n_in,
                              void* d_out, int out_size, void* d_ws,
                              size_t ws_size, hipStream_t stream) {
    const float* m = (const float*)d_in[0];
    const int* nrows = (const int*)d_in[1];
    const int* ncols = (const int*)d_in[2];
    const int B = in_sizes[1];

    char* ws = (char*)d_ws;
    unsigned* bar = (unsigned*)ws;          // 4KB
    float* P = (float*)(ws + (1u << 20));   // 2 x 4MB
    h16* mh = (h16*)(ws + (16u << 20));     // 128MB
    float* out = (float*)d_out;

    const int nbar = B * 16;
    zero_bar<<<dim3((nbar + 255) / 256), dim3(256), 0, stream>>>(bar, nbar);

    sinkhorn_fused<<<dim3(B * NBLK), dim3(256), 0, stream>>>(
        m, nrows, ncols, P, mh, bar, out, B);
}